// Round 15
// baseline (636.473 us; speedup 1.0000x reference)
//
#include <hip/hip_runtime.h>
#include <hip/hip_bf16.h>
#include <math.h>

#define NPTS 4096
#define KD   64
#define BR   64                       // rows per block (4 waves x 16 rows)
#define BC   128                      // cols per tile
#define NSPLIT 8                      // column splits (r15: 4 -> 8 => 2048 blocks
                                      // = 8 blocks/CU; kernel is 64-VGPR/18KB so
                                      // HW can host 8 -> doubles waves/SIMD)
#define CT   (NPTS / (BC * NSPLIT))   // 4 col tiles per block
#define NTHREADS 256
#define BLOG2 (-12.0f)                // -log2(4096)
#define LOG2E 1.4426950408889634f
#define LN2   0.6931471805599453f

typedef float f32x4 __attribute__((ext_vector_type(4)));

// fast transcendentals: raw v_exp_f32 / v_log_f32 (base-2, <=1 ulp)
__device__ __forceinline__ float ex2(float x) {
#if __has_builtin(__builtin_amdgcn_exp2f)
  return __builtin_amdgcn_exp2f(x);
#else
  return exp2f(x);
#endif
}
__device__ __forceinline__ float lg2(float x) {
#if __has_builtin(__builtin_amdgcn_logf)
  return __builtin_amdgcn_logf(x);   // v_log_f32 = log2
#else
  return log2f(x);
#endif
}

// pack 4 floats -> 4 OCP e4m3 bytes (v_cvt_pk_fp8_f32, RNE)
__device__ __forceinline__ unsigned pack4_fp8(float a, float b, float c, float d) {
  int v = __builtin_amdgcn_cvt_pk_fp8_f32(a, b, 0, false);   // bytes 0,1
  v = __builtin_amdgcn_cvt_pk_fp8_f32(c, d, v, true);        // bytes 2,3
  return (unsigned)v;
}

struct FusedArgs {
  const unsigned char* X[4];   // fp8 e4m3 interleaved rows [NPTS][64 B]
  const unsigned char* Y[4];
  const float* csq[4];    // 0.5*|y_j|^2 of col-side points of dir d
  const float* pmr[4];    // prev-pass partials [NSPLIT][NPTS], paired dir
  const float* psr[4];
  const float* potr[4];   // prev potential of col-side points (paired dir)
  float* potw[4];         // blended potential out (paired dir slot)
  float* pm;              // this pass: [4][NSPLIT][NPTS] partial max (base-2)
  float* ps;              // this pass: [4][NSPLIT][NPTS] partial sum
  float ie2;              // log2(e) / eps_cur
  float elp;              // eps_prev * ln(2)
  float alpha, beta;      // potential blend g = alpha*prev + beta*v
  int mode;               // 0 = init (g = 0, no partials), 1 = merge prev pass
};

// async 16B/lane global->LDS; lds dest = wave-uniform base + lane*16
__device__ __forceinline__ void gll16(const void* g, void* l) {
  __builtin_amdgcn_global_load_lds(
      (const __attribute__((address_space(1))) void*)g,
      (__attribute__((address_space(3))) void*)l, 16, 0, 0);
}

// One softmin pass, all 4 directions via blockIdx.z — r13 verified kernel
// (582us; fp8 e4m3 16x16x32 MFMA, interleaved-K rows).
// ROUND-15 delta (sole change): NSPLIT 4 -> 8. r14's counters showed this
// kernel compiles to 64 VGPRs with 18 KB LDS -> HW can host 8 blocks/CU, but
// the old 1024-block grid supplied only 4. The kernel is wait-bound
// (pipe-sum ~8-10us vs ~21.5us measured); doubling resident waves/SIMD
// (4 -> 8) is the remaining verified-safe lever. Per-block work halves
// (CT=4); partials widen to NSPLIT=8 (8-way merge shape verified in r9/r10).
__global__ __launch_bounds__(NTHREADS, 4)
void fused_softmin(FusedArgs A) {
  __shared__ __align__(16) unsigned char YT[2][BC * KD];  // 2 x 8 KB fp8
  __shared__ __align__(16) float QL[BC * CT];             // 2 KB: split's q

  const int tid  = threadIdx.x;
  const int lane = tid & 63;
  const int wave = tid >> 6;
  const int ln16 = lane & 15;   // A row / B,C col within 16
  const int rg   = lane >> 4;   // k-octet for A/B; row-quad for C
  const int rowblk = blockIdx.x;
  const int split  = blockIdx.y;
  const int dir    = blockIdx.z;

  const unsigned char* __restrict__ Xb = A.X[dir];
  const unsigned char* __restrict__ Yb = A.Y[dir];
  const float ie2 = A.ie2;
  const int row0 = rowblk * BR;
  const int col0 = split * (CT * BC);

  // staging geometry: idx = it*256 + tid; col r = idx>>2, seg q = idx&3
  const int srow = tid >> 2;     // 0..63 (+ it*64)
  const int sseg = tid & 3;

  // issue tile-0 Y staging (async): 2 issues x 256 thr x 16 B = 8 KB
#pragma unroll
  for (int it = 0; it < 2; ++it) {
    int r = it * 64 + srow;
    gll16(Yb + (size_t)(col0 + r) * KD + ((sseg ^ (r & 3)) << 4),
          (unsigned char*)YT[0] + it * 4096 + wave * 1024);
  }

  // A fragments: one 16B load -> both K=32 chunk octets (interleaved rows)
  long a0, a1;
  {
    const unsigned char* ap = Xb + (size_t)(row0 + wave * 16 + ln16) * KD + rg * 16;
    union { uint4 u; long l[2]; } t;
    t.u = *(const uint4*)ap;
    a0 = t.l[0]; a1 = t.l[1];
  }

  // ---- fused merge prologue: build q for this split's 512 cols ----
  {
    const float* __restrict__ csq = A.csq[dir];
    if (A.mode == 0) {
#pragma unroll
      for (int i = 0; i < 2; ++i) {
        int c = col0 + tid + i * 256;
        QL[tid + i * 256] = BLOG2 - csq[c] * ie2;     // g = 0
      }
    } else {
      const float* __restrict__ pmr = A.pmr[dir];
      const float* __restrict__ psr = A.psr[dir];
      const float* __restrict__ potr = A.potr[dir];
      float* __restrict__ potw = A.potw[dir];
#pragma unroll
      for (int i = 0; i < 2; ++i) {
        int c = col0 + tid + i * 256;
        float mv[NSPLIT], sv[NSPLIT];
        float m8 = -__builtin_inff();
#pragma unroll
        for (int sp = 0; sp < NSPLIT; ++sp) {
          mv[sp] = pmr[sp * NPTS + c];
          sv[sp] = psr[sp * NPTS + c];
          m8 = fmaxf(m8, mv[sp]);
        }
        float s8 = 0.f;
#pragma unroll
        for (int sp = 0; sp < NSPLIT; ++sp) s8 += sv[sp] * ex2(mv[sp] - m8);
        float lse2 = m8 + lg2(s8);
        float xsq = csq[c];
        float v = xsq - A.elp * lse2;                 // elp = eps_prev*ln2
        float g = A.alpha * potr[c] + A.beta * v;
        if (rowblk == 0) potw[c] = g;
        QL[tid + i * 256] = BLOG2 + (g - xsq) * ie2;
      }
    }
  }

  float m[4], s[4];
#pragma unroll
  for (int r = 0; r < 4; ++r) { m[r] = -__builtin_inff(); s[r] = 0.f; }

  // per-lane constant B-read offset: col seg position = rg ^ (col&3)
  const int boff = ln16 * KD + ((rg ^ (ln16 & 3)) << 4);

  __syncthreads();   // drains tile-0 staging; QL visible to all waves

  for (int tile = 0; tile < CT; ++tile) {
    const int cb = tile & 1;

    // async prefetch next tile (drained by end-of-tile barrier)
    if (tile < CT - 1) {
      const int nc0 = col0 + (tile + 1) * BC;
#pragma unroll
      for (int it = 0; it < 2; ++it) {
        int r = it * 64 + srow;
        gll16(Yb + (size_t)(nc0 + r) * KD + ((sseg ^ (r & 3)) << 4),
              (unsigned char*)YT[cb ^ 1] + it * 4096 + wave * 1024);
      }
    }

    float qv[8];
#pragma unroll
    for (int t = 0; t < 8; ++t) qv[t] = QL[tile * BC + t * 16 + ln16];

    f32x4 acc[8];
#pragma unroll
    for (int t = 0; t < 8; ++t)
#pragma unroll
      for (int i = 0; i < 4; ++i) acc[t][i] = 0.f;

    const unsigned char* ybase = YT[cb] + boff;
#pragma unroll
    for (int t = 0; t < 8; ++t) {
      union { uint4 u; long l[2]; } bb;
      bb.u = *(const uint4*)(ybase + t * 16 * KD);
      acc[t] = __builtin_amdgcn_mfma_f32_16x16x32_fp8_fp8(a0, bb.l[0], acc[t], 0, 0, 0);
      acc[t] = __builtin_amdgcn_mfma_f32_16x16x32_fp8_fp8(a1, bb.l[1], acc[t], 0, 0, 0);
    }

#pragma unroll
    for (int r = 0; r < 4; ++r) {
      float l[8];
#pragma unroll
      for (int t = 0; t < 8; ++t) l[t] = fmaf(acc[t][r], ie2, qv[t]);
      float tmax = -__builtin_inff();
#pragma unroll
      for (int t = 0; t < 8; ++t) tmax = fmaxf(tmax, l[t]);
      float mn = fmaxf(m[r], tmax);
      float sadd = 0.f;
#pragma unroll
      for (int t = 0; t < 8; ++t) sadd += ex2(l[t] - mn);
      s[r] = fmaf(s[r], ex2(m[r] - mn), sadd);
      m[r] = mn;
    }
    __syncthreads();
  }

  // cross-lane merge over the 16 col-owner lanes (masks 1..8 keep rg)
#pragma unroll
  for (int r = 0; r < 4; ++r) {
#pragma unroll
    for (int d = 1; d < 16; d <<= 1) {
      float mo = __shfl_xor(m[r], d, 64);
      float so = __shfl_xor(s[r], d, 64);
      float mn = fmaxf(m[r], mo);
      s[r] = ex2(m[r] - mn) * s[r] + ex2(mo - mn) * so;
      m[r] = mn;
    }
  }
  if (ln16 == 0) {
#pragma unroll
    for (int r = 0; r < 4; ++r) {
      int row = row0 + wave * 16 + rg * 4 + r;
      size_t gi = (size_t)(dir * NSPLIT + split) * NPTS + row;
      A.pm[gi] = m[r];
      A.ps[gi] = s[r];
    }
  }
}

// sqnorms + fp8 e4m3 conversion with k-interleave:
// out seg g (16 B) = fp8(k[8g..8g+7]) || fp8(k[32+8g..32+8g+7])
__global__ void prep(const float* __restrict__ x, const float* __restrict__ y,
                     float* xs, float* ys,
                     unsigned char* xq, unsigned char* yq) {
  int gid = blockIdx.x * blockDim.x + threadIdx.x;  // 0..8191
  int isx = (gid < NPTS) ? 1 : 0;
  const float* p = isx ? x : y;
  int row = gid & (NPTS - 1);
  const float4* r4p = (const float4*)(p + (size_t)row * KD);
  float4 r4[16];
  float s = 0.f;
#pragma unroll
  for (int i = 0; i < 16; ++i) {
    r4[i] = r4p[i];
    s += r4[i].x * r4[i].x + r4[i].y * r4[i].y +
         r4[i].z * r4[i].z + r4[i].w * r4[i].w;
  }
  unsigned char* ob = (isx ? xq : yq) + (size_t)row * KD;
#pragma unroll
  for (int g = 0; g < 4; ++g) {
    uint4 d;
    float4 lo0 = r4[2 * g], lo1 = r4[2 * g + 1];
    float4 hi0 = r4[8 + 2 * g], hi1 = r4[8 + 2 * g + 1];
    d.x = pack4_fp8(lo0.x, lo0.y, lo0.z, lo0.w);
    d.y = pack4_fp8(lo1.x, lo1.y, lo1.z, lo1.w);
    d.z = pack4_fp8(hi0.x, hi0.y, hi0.z, hi0.w);
    d.w = pack4_fp8(hi1.x, hi1.y, hi1.z, hi1.w);
    *(uint4*)(ob + g * 16) = d;
  }
  (isx ? xs : ys)[row] = 0.5f * s;
}

// Two-stage final reduction (round-10 verified; NSPLIT=8 merge as in r9)
__global__ void final_partial(const float* __restrict__ pm,
                              const float* __restrict__ ps,
                              const float* __restrict__ xsx,
                              const float* __restrict__ xsy,
                              float elpF, float* blkout) {
  __shared__ float red[256];
  int t = threadIdx.x;
  int gid = blockIdx.x * 256 + t;        // 0..16383 = (dir, row)
  int d = gid >> 12;
  int r = gid & (NPTS - 1);
  float mv[NSPLIT], sv[NSPLIT];
  float m8 = -__builtin_inff();
#pragma unroll
  for (int sp = 0; sp < NSPLIT; ++sp) {
    mv[sp] = pm[(size_t)(d * NSPLIT + sp) * NPTS + r];
    sv[sp] = ps[(size_t)(d * NSPLIT + sp) * NPTS + r];
    m8 = fmaxf(m8, mv[sp]);
  }
  float s8 = 0.f;
#pragma unroll
  for (int sp = 0; sp < NSPLIT; ++sp) s8 += sv[sp] * ex2(mv[sp] - m8);
  float lse2 = m8 + lg2(s8);
  float xsq = (d == 0 || d == 2) ? xsx[r] : xsy[r];
  float f = xsq - elpF * lse2;
  red[t] = (d < 2) ? f : -f;
  __syncthreads();
  for (int off = 128; off > 0; off >>= 1) {
    if (t < off) red[t] += red[t + off];
    __syncthreads();
  }
  if (t == 0) blkout[blockIdx.x] = red[0];
}

__global__ void final_sum(const float* __restrict__ blkin, float* out) {
  int t = threadIdx.x;   // 64 threads = 1 wave
  float v = blkin[t];
#pragma unroll
  for (int d = 1; d < 64; d <<= 1) v += __shfl_xor(v, d, 64);
  if (t == 0) out[0] = v * (1.0f / NPTS);
}

extern "C" void kernel_launch(void* const* d_in, const int* in_sizes, int n_in,
                              void* d_out, int out_size, void* d_ws, size_t ws_size,
                              hipStream_t stream) {
  const float* x = (const float*)d_in[0];
  const float* y = (const float*)d_in[1];
  float* out = (float*)d_out;
  float* w = (float*)d_ws;

  // ws layout (float slots); total ~171*NPTS ~ 2.8 MB
  float* xs_x = w;                         // [NPTS]
  float* xs_y = w + NPTS;                  // [NPTS]
  float* pot0 = w + 2 * NPTS;              // [4][NPTS] potential ping
  float* pot1 = w + 6 * NPTS;              // [4][NPTS] potential pong
  float* pm0  = w + 10 * NPTS;             // [4][NSPLIT=8][NPTS] = 32N
  float* ps0  = w + 42 * NPTS;
  float* pm1  = w + 74 * NPTS;
  float* ps1  = w + 106 * NPTS;
  float* blkp = w + 138 * NPTS;            // [64] stage-1 partials
  unsigned char* xq = (unsigned char*)(w + 139 * NPTS);  // [NPTS][64 B] fp8
  unsigned char* yq = (unsigned char*)(w + 155 * NPTS);  // [NPTS][64 B] fp8
  float* pmb[2] = {pm0, pm1};
  float* psb[2] = {ps0, ps1};
  float* potb[2] = {pot0, pot1};

  // geomloss epsilon_schedule(p=2, diameter=20, blur=0.01, scaling=0.7)
  double eps_list[32];
  int neps = 0;
  {
    double start = 2.0 * log(20.0);
    double stop  = 2.0 * log(0.01);
    double step  = 2.0 * log(0.7);
    eps_list[neps++] = 400.0;
    int cnt = (int)ceil((stop - start) / step);  // 22
    for (int i = 0; i < cnt && neps < 30; ++i) eps_list[neps++] = exp(start + (double)i * step);
    eps_list[neps++] = 1e-4;                     // neps == 24
  }

  // dir 0: ft (rows x, cols y); dir 1: gt (rows y, cols x)
  // dir 2: f_aa (x,x); dir 3: g_bb (y,y).  qpair = paired dir whose ROWS are
  // this dir's COLS: {1,0,2,3}.
  const unsigned char* Xd[4] = {xq, yq, xq, yq};
  const unsigned char* Yd[4] = {yq, xq, xq, yq};
  const float* YSQd[4] = {xs_y, xs_x, xs_x, xs_y};   // col-side sqnorms
  const int qpair[4] = {1, 0, 2, 3};

  prep<<<dim3(32), dim3(256), 0, stream>>>(x, y, xs_x, xs_y, xq, yq);

  dim3 fgrid(NPTS / BR, NSPLIT, 4);   // 64 x 8 x 4 = 2048 blocks = 8/CU

  // eps used by launch k (k = 0 init, 1..24 loop, 25 final extrapolation)
  double ecur[26];
  ecur[0] = eps_list[0];
  for (int k = 1; k <= 24; ++k) ecur[k] = eps_list[k - 1];
  ecur[25] = eps_list[neps - 1];

  for (int k = 0; k <= 25; ++k) {
    FusedArgs fa;
    for (int d = 0; d < 4; ++d) {
      fa.X[d] = Xd[d]; fa.Y[d] = Yd[d]; fa.csq[d] = YSQd[d];
      int p = qpair[d];
      fa.pmr[d]  = pmb[(k + 1) & 1] + (size_t)p * NSPLIT * NPTS;
      fa.psr[d]  = psb[(k + 1) & 1] + (size_t)p * NSPLIT * NPTS;
      fa.potr[d] = potb[(k + 1) & 1] + (size_t)p * NPTS;
      fa.potw[d] = potb[k & 1] + (size_t)p * NPTS;
    }
    fa.pm = pmb[k & 1];
    fa.ps = psb[k & 1];
    fa.ie2 = (float)(LOG2E / ecur[k]);
    fa.elp = (k == 0) ? 0.f : (float)(ecur[k - 1] * LN2);
    fa.alpha = (k <= 1) ? 0.f : 0.5f;
    fa.beta  = (k <= 1) ? 1.f : 0.5f;
    fa.mode  = (k == 0) ? 0 : 1;
    fused_softmin<<<fgrid, dim3(NTHREADS), 0, stream>>>(fa);
  }

  final_partial<<<dim3(64), dim3(256), 0, stream>>>(
      pmb[25 & 1], psb[25 & 1], xs_x, xs_y,
      (float)(eps_list[neps - 1] * LN2), blkp);
  final_sum<<<dim3(1), dim3(64), 0, stream>>>(blkp, out);
}

// Round 16
// 582.318 us; speedup vs baseline: 1.0930x; 1.0930x over previous
//
#include <hip/hip_runtime.h>
#include <hip/hip_bf16.h>
#include <math.h>

#define NPTS 4096
#define KD   64
#define BR   64                       // rows per block (4 waves x 16 rows)
#define BC   128                      // cols per tile
#define NSPLIT 4                      // column splits (partial LSE per split)
#define CT   (NPTS / (BC * NSPLIT))   // 8 col tiles per block
#define NTHREADS 256
#define BLOG2 (-12.0f)                // -log2(4096)
#define LOG2E 1.4426950408889634f
#define LN2   0.6931471805599453f

typedef float f32x4 __attribute__((ext_vector_type(4)));

// fast transcendentals: raw v_exp_f32 / v_log_f32 (base-2, <=1 ulp)
__device__ __forceinline__ float ex2(float x) {
#if __has_builtin(__builtin_amdgcn_exp2f)
  return __builtin_amdgcn_exp2f(x);
#else
  return exp2f(x);
#endif
}
__device__ __forceinline__ float lg2(float x) {
#if __has_builtin(__builtin_amdgcn_logf)
  return __builtin_amdgcn_logf(x);   // v_log_f32 = log2
#else
  return log2f(x);
#endif
}

// pack 4 floats -> 4 OCP e4m3 bytes (v_cvt_pk_fp8_f32, RNE)
__device__ __forceinline__ unsigned pack4_fp8(float a, float b, float c, float d) {
  int v = __builtin_amdgcn_cvt_pk_fp8_f32(a, b, 0, false);   // bytes 0,1
  v = __builtin_amdgcn_cvt_pk_fp8_f32(c, d, v, true);        // bytes 2,3
  return (unsigned)v;
}

struct FusedArgs {
  const unsigned char* X[4];   // fp8 e4m3 interleaved rows [NPTS][64 B]
  const unsigned char* Y[4];
  const float* csq[4];    // 0.5*|y_j|^2 of col-side points of dir d
  const float* pmr[4];    // prev-pass partials [NSPLIT][NPTS], paired dir
  const float* psr[4];
  const float* potr[4];   // prev potential of col-side points (paired dir)
  float* potw[4];         // blended potential out (paired dir slot)
  float* pm;              // this pass: [4][NSPLIT][NPTS] partial max (base-2)
  float* ps;              // this pass: [4][NSPLIT][NPTS] partial sum
  float ie2;              // log2(e) / eps_cur
  float elp;              // eps_prev * ln(2)
  float alpha, beta;      // potential blend g = alpha*prev + beta*v
  int mode;               // 0 = init (g = 0, no partials), 1 = merge prev pass
};

// async 16B/lane global->LDS; lds dest = wave-uniform base + lane*16
__device__ __forceinline__ void gll16(const void* g, void* l) {
  __builtin_amdgcn_global_load_lds(
      (const __attribute__((address_space(1))) void*)g,
      (__attribute__((address_space(3))) void*)l, 16, 0, 0);
}

// One softmin pass, all 4 directions via blockIdx.z — the r13 VERIFIED BEST
// (582.6us, absmax 0.0). fp8 e4m3 16x16x32 MFMA, interleaved-K rows, 1024
// blocks = 4 blocks/CU, fused q-merge prologue, two-stage final reduction.
// Structural levers individually falsified around this point: fragment
// sharing (r6/r9: spill/overhead), 32x32 shape (r8/r11: occupancy/tile
// size), fewer barriers (r14: neutral), more blocks/CU (r15: prologue
// doubles, regressed). Residual wait (~2x pipe-sum) is latency-structural
// to the barrier-synced K-loop (cf. m97 plateau, m131-m141).
__global__ __launch_bounds__(NTHREADS, 4)
void fused_softmin(FusedArgs A) {
  __shared__ __align__(16) unsigned char YT[2][BC * KD];  // 2 x 8 KB fp8
  __shared__ __align__(16) float QL[BC * CT];             // 4 KB: split's q

  const int tid  = threadIdx.x;
  const int lane = tid & 63;
  const int wave = tid >> 6;
  const int ln16 = lane & 15;   // A row / B,C col within 16
  const int rg   = lane >> 4;   // k-octet for A/B; row-quad for C
  const int rowblk = blockIdx.x;
  const int split  = blockIdx.y;
  const int dir    = blockIdx.z;

  const unsigned char* __restrict__ Xb = A.X[dir];
  const unsigned char* __restrict__ Yb = A.Y[dir];
  const float ie2 = A.ie2;
  const int row0 = rowblk * BR;
  const int col0 = split * (CT * BC);

  // staging geometry: idx = it*256 + tid; col r = idx>>2, seg q = idx&3
  const int srow = tid >> 2;     // 0..63 (+ it*64)
  const int sseg = tid & 3;

  // issue tile-0 Y staging (async): 2 issues x 256 thr x 16 B = 8 KB
#pragma unroll
  for (int it = 0; it < 2; ++it) {
    int r = it * 64 + srow;
    gll16(Yb + (size_t)(col0 + r) * KD + ((sseg ^ (r & 3)) << 4),
          (unsigned char*)YT[0] + it * 4096 + wave * 1024);
  }

  // A fragments: one 16B load -> both K=32 chunk octets (interleaved rows)
  long a0, a1;
  {
    const unsigned char* ap = Xb + (size_t)(row0 + wave * 16 + ln16) * KD + rg * 16;
    union { uint4 u; long l[2]; } t;
    t.u = *(const uint4*)ap;
    a0 = t.l[0]; a1 = t.l[1];
  }

  // ---- fused merge prologue: build q for this split's 1024 cols ----
  {
    const float* __restrict__ csq = A.csq[dir];
    if (A.mode == 0) {
#pragma unroll
      for (int i = 0; i < 4; ++i) {
        int c = col0 + tid + i * 256;
        QL[tid + i * 256] = BLOG2 - csq[c] * ie2;     // g = 0
      }
    } else {
      const float* __restrict__ pmr = A.pmr[dir];
      const float* __restrict__ psr = A.psr[dir];
      const float* __restrict__ potr = A.potr[dir];
      float* __restrict__ potw = A.potw[dir];
#pragma unroll
      for (int i = 0; i < 4; ++i) {
        int c = col0 + tid + i * 256;
        float m0 = pmr[0 * NPTS + c], m1 = pmr[1 * NPTS + c];
        float m2 = pmr[2 * NPTS + c], m3 = pmr[3 * NPTS + c];
        float s0 = psr[0 * NPTS + c], s1 = psr[1 * NPTS + c];
        float s2 = psr[2 * NPTS + c], s3 = psr[3 * NPTS + c];
        float m4 = fmaxf(fmaxf(m0, m1), fmaxf(m2, m3));
        float s4 = s0 * ex2(m0 - m4) + s1 * ex2(m1 - m4) +
                   s2 * ex2(m2 - m4) + s3 * ex2(m3 - m4);
        float lse2 = m4 + lg2(s4);
        float xsq = csq[c];
        float v = xsq - A.elp * lse2;                 // elp = eps_prev*ln2
        float g = A.alpha * potr[c] + A.beta * v;
        if (rowblk == 0) potw[c] = g;
        QL[tid + i * 256] = BLOG2 + (g - xsq) * ie2;
      }
    }
  }

  float m[4], s[4];
#pragma unroll
  for (int r = 0; r < 4; ++r) { m[r] = -__builtin_inff(); s[r] = 0.f; }

  // per-lane constant B-read offset: col seg position = rg ^ (col&3)
  const int boff = ln16 * KD + ((rg ^ (ln16 & 3)) << 4);

  __syncthreads();   // drains tile-0 staging; QL visible to all waves

  for (int tile = 0; tile < CT; ++tile) {
    const int cb = tile & 1;

    // async prefetch next tile (drained by end-of-tile barrier)
    if (tile < CT - 1) {
      const int nc0 = col0 + (tile + 1) * BC;
#pragma unroll
      for (int it = 0; it < 2; ++it) {
        int r = it * 64 + srow;
        gll16(Yb + (size_t)(nc0 + r) * KD + ((sseg ^ (r & 3)) << 4),
              (unsigned char*)YT[cb ^ 1] + it * 4096 + wave * 1024);
      }
    }

    float qv[8];
#pragma unroll
    for (int t = 0; t < 8; ++t) qv[t] = QL[tile * BC + t * 16 + ln16];

    f32x4 acc[8];
#pragma unroll
    for (int t = 0; t < 8; ++t)
#pragma unroll
      for (int i = 0; i < 4; ++i) acc[t][i] = 0.f;

    const unsigned char* ybase = YT[cb] + boff;
#pragma unroll
    for (int t = 0; t < 8; ++t) {
      union { uint4 u; long l[2]; } bb;
      bb.u = *(const uint4*)(ybase + t * 16 * KD);
      acc[t] = __builtin_amdgcn_mfma_f32_16x16x32_fp8_fp8(a0, bb.l[0], acc[t], 0, 0, 0);
      acc[t] = __builtin_amdgcn_mfma_f32_16x16x32_fp8_fp8(a1, bb.l[1], acc[t], 0, 0, 0);
    }

#pragma unroll
    for (int r = 0; r < 4; ++r) {
      float l[8];
#pragma unroll
      for (int t = 0; t < 8; ++t) l[t] = fmaf(acc[t][r], ie2, qv[t]);
      float tmax = -__builtin_inff();
#pragma unroll
      for (int t = 0; t < 8; ++t) tmax = fmaxf(tmax, l[t]);
      float mn = fmaxf(m[r], tmax);
      float sadd = 0.f;
#pragma unroll
      for (int t = 0; t < 8; ++t) sadd += ex2(l[t] - mn);
      s[r] = fmaf(s[r], ex2(m[r] - mn), sadd);
      m[r] = mn;
    }
    __syncthreads();
  }

  // cross-lane merge over the 16 col-owner lanes (masks 1..8 keep rg)
#pragma unroll
  for (int r = 0; r < 4; ++r) {
#pragma unroll
    for (int d = 1; d < 16; d <<= 1) {
      float mo = __shfl_xor(m[r], d, 64);
      float so = __shfl_xor(s[r], d, 64);
      float mn = fmaxf(m[r], mo);
      s[r] = ex2(m[r] - mn) * s[r] + ex2(mo - mn) * so;
      m[r] = mn;
    }
  }
  if (ln16 == 0) {
#pragma unroll
    for (int r = 0; r < 4; ++r) {
      int row = row0 + wave * 16 + rg * 4 + r;
      size_t gi = (size_t)(dir * NSPLIT + split) * NPTS + row;
      A.pm[gi] = m[r];
      A.ps[gi] = s[r];
    }
  }
}

// sqnorms + fp8 e4m3 conversion with k-interleave:
// out seg g (16 B) = fp8(k[8g..8g+7]) || fp8(k[32+8g..32+8g+7])
__global__ void prep(const float* __restrict__ x, const float* __restrict__ y,
                     float* xs, float* ys,
                     unsigned char* xq, unsigned char* yq) {
  int gid = blockIdx.x * blockDim.x + threadIdx.x;  // 0..8191
  int isx = (gid < NPTS) ? 1 : 0;
  const float* p = isx ? x : y;
  int row = gid & (NPTS - 1);
  const float4* r4p = (const float4*)(p + (size_t)row * KD);
  float4 r4[16];
  float s = 0.f;
#pragma unroll
  for (int i = 0; i < 16; ++i) {
    r4[i] = r4p[i];
    s += r4[i].x * r4[i].x + r4[i].y * r4[i].y +
         r4[i].z * r4[i].z + r4[i].w * r4[i].w;
  }
  unsigned char* ob = (isx ? xq : yq) + (size_t)row * KD;
#pragma unroll
  for (int g = 0; g < 4; ++g) {
    uint4 d;
    float4 lo0 = r4[2 * g], lo1 = r4[2 * g + 1];
    float4 hi0 = r4[8 + 2 * g], hi1 = r4[8 + 2 * g + 1];
    d.x = pack4_fp8(lo0.x, lo0.y, lo0.z, lo0.w);
    d.y = pack4_fp8(lo1.x, lo1.y, lo1.z, lo1.w);
    d.z = pack4_fp8(hi0.x, hi0.y, hi0.z, hi0.w);
    d.w = pack4_fp8(hi1.x, hi1.y, hi1.z, hi1.w);
    *(uint4*)(ob + g * 16) = d;
  }
  (isx ? xs : ys)[row] = 0.5f * s;
}

// Two-stage final reduction (round-10 verified)
__global__ void final_partial(const float* __restrict__ pm,
                              const float* __restrict__ ps,
                              const float* __restrict__ xsx,
                              const float* __restrict__ xsy,
                              float elpF, float* blkout) {
  __shared__ float red[256];
  int t = threadIdx.x;
  int gid = blockIdx.x * 256 + t;        // 0..16383 = (dir, row)
  int d = gid >> 12;
  int r = gid & (NPTS - 1);
  float m0 = pm[(size_t)(d * NSPLIT + 0) * NPTS + r];
  float m1 = pm[(size_t)(d * NSPLIT + 1) * NPTS + r];
  float m2 = pm[(size_t)(d * NSPLIT + 2) * NPTS + r];
  float m3 = pm[(size_t)(d * NSPLIT + 3) * NPTS + r];
  float s0 = ps[(size_t)(d * NSPLIT + 0) * NPTS + r];
  float s1 = ps[(size_t)(d * NSPLIT + 1) * NPTS + r];
  float s2 = ps[(size_t)(d * NSPLIT + 2) * NPTS + r];
  float s3 = ps[(size_t)(d * NSPLIT + 3) * NPTS + r];
  float m4 = fmaxf(fmaxf(m0, m1), fmaxf(m2, m3));
  float s4 = s0 * ex2(m0 - m4) + s1 * ex2(m1 - m4) +
             s2 * ex2(m2 - m4) + s3 * ex2(m3 - m4);
  float lse2 = m4 + lg2(s4);
  float xsq = (d == 0 || d == 2) ? xsx[r] : xsy[r];
  float f = xsq - elpF * lse2;
  red[t] = (d < 2) ? f : -f;
  __syncthreads();
  for (int off = 128; off > 0; off >>= 1) {
    if (t < off) red[t] += red[t + off];
    __syncthreads();
  }
  if (t == 0) blkout[blockIdx.x] = red[0];
}

__global__ void final_sum(const float* __restrict__ blkin, float* out) {
  int t = threadIdx.x;   // 64 threads = 1 wave
  float v = blkin[t];
#pragma unroll
  for (int d = 1; d < 64; d <<= 1) v += __shfl_xor(v, d, 64);
  if (t == 0) out[0] = v * (1.0f / NPTS);
}

extern "C" void kernel_launch(void* const* d_in, const int* in_sizes, int n_in,
                              void* d_out, int out_size, void* d_ws, size_t ws_size,
                              hipStream_t stream) {
  const float* x = (const float*)d_in[0];
  const float* y = (const float*)d_in[1];
  float* out = (float*)d_out;
  float* w = (float*)d_ws;

  // ws layout (float slots); total ~107*NPTS ~ 1.8 MB
  float* xs_x = w;                         // [NPTS]
  float* xs_y = w + NPTS;                  // [NPTS]
  float* pot0 = w + 2 * NPTS;              // [4][NPTS] potential ping
  float* pot1 = w + 6 * NPTS;              // [4][NPTS] potential pong
  float* pm0  = w + 10 * NPTS;             // [4][NSPLIT][NPTS]
  float* ps0  = w + 26 * NPTS;
  float* pm1  = w + 42 * NPTS;
  float* ps1  = w + 58 * NPTS;
  float* blkp = w + 74 * NPTS;             // [64] stage-1 partials
  unsigned char* xq = (unsigned char*)(w + 75 * NPTS);   // [NPTS][64 B] fp8
  unsigned char* yq = (unsigned char*)(w + 91 * NPTS);   // [NPTS][64 B] fp8
  float* pmb[2] = {pm0, pm1};
  float* psb[2] = {ps0, ps1};
  float* potb[2] = {pot0, pot1};

  // geomloss epsilon_schedule(p=2, diameter=20, blur=0.01, scaling=0.7)
  double eps_list[32];
  int neps = 0;
  {
    double start = 2.0 * log(20.0);
    double stop  = 2.0 * log(0.01);
    double step  = 2.0 * log(0.7);
    eps_list[neps++] = 400.0;
    int cnt = (int)ceil((stop - start) / step);  // 22
    for (int i = 0; i < cnt && neps < 30; ++i) eps_list[neps++] = exp(start + (double)i * step);
    eps_list[neps++] = 1e-4;                     // neps == 24
  }

  // dir 0: ft (rows x, cols y); dir 1: gt (rows y, cols x)
  // dir 2: f_aa (x,x); dir 3: g_bb (y,y).  qpair = paired dir whose ROWS are
  // this dir's COLS: {1,0,2,3}.
  const unsigned char* Xd[4] = {xq, yq, xq, yq};
  const unsigned char* Yd[4] = {yq, xq, xq, yq};
  const float* YSQd[4] = {xs_y, xs_x, xs_x, xs_y};   // col-side sqnorms
  const int qpair[4] = {1, 0, 2, 3};

  prep<<<dim3(32), dim3(256), 0, stream>>>(x, y, xs_x, xs_y, xq, yq);

  dim3 fgrid(NPTS / BR, NSPLIT, 4);   // 64 x 4 x 4 = 1024 blocks = 4/CU

  // eps used by launch k (k = 0 init, 1..24 loop, 25 final extrapolation)
  double ecur[26];
  ecur[0] = eps_list[0];
  for (int k = 1; k <= 24; ++k) ecur[k] = eps_list[k - 1];
  ecur[25] = eps_list[neps - 1];

  for (int k = 0; k <= 25; ++k) {
    FusedArgs fa;
    for (int d = 0; d < 4; ++d) {
      fa.X[d] = Xd[d]; fa.Y[d] = Yd[d]; fa.csq[d] = YSQd[d];
      int p = qpair[d];
      fa.pmr[d]  = pmb[(k + 1) & 1] + (size_t)p * NSPLIT * NPTS;
      fa.psr[d]  = psb[(k + 1) & 1] + (size_t)p * NSPLIT * NPTS;
      fa.potr[d] = potb[(k + 1) & 1] + (size_t)p * NPTS;
      fa.potw[d] = potb[k & 1] + (size_t)p * NPTS;
    }
    fa.pm = pmb[k & 1];
    fa.ps = psb[k & 1];
    fa.ie2 = (float)(LOG2E / ecur[k]);
    fa.elp = (k == 0) ? 0.f : (float)(ecur[k - 1] * LN2);
    fa.alpha = (k <= 1) ? 0.f : 0.5f;
    fa.beta  = (k <= 1) ? 1.f : 0.5f;
    fa.mode  = (k == 0) ? 0 : 1;
    fused_softmin<<<fgrid, dim3(NTHREADS), 0, stream>>>(fa);
  }

  final_partial<<<dim3(64), dim3(256), 0, stream>>>(
      pmb[25 & 1], psb[25 & 1], xs_x, xs_y,
      (float)(eps_list[neps - 1] * LN2), blkp);
  final_sum<<<dim3(1), dim3(64), 0, stream>>>(blkp, out);
}